// Round 6
// baseline (1330.779 us; speedup 1.0000x reference)
//
#include <hip/hip_runtime.h>

typedef float f32x4 __attribute__((ext_vector_type(4)));
typedef float f32x2 __attribute__((ext_vector_type(2)));
typedef short s16x8 __attribute__((ext_vector_type(8)));
typedef __bf16 bf16x8 __attribute__((ext_vector_type(8)));

__device__ __forceinline__ unsigned short f2bf(float f) {
    unsigned int u = __builtin_bit_cast(unsigned int, f);
    u += 0x7FFFu + ((u >> 16) & 1u);
    return (unsigned short)(u >> 16);
}

__device__ __forceinline__ f32x4 MFMA(s16x8 a, s16x8 b, f32x4 c) {
    return __builtin_amdgcn_mfma_f32_16x16x32_bf16(
        __builtin_bit_cast(bf16x8, a), __builtin_bit_cast(bf16x8, b), c, 0, 0, 0);
}

__device__ __forceinline__ float sigm(float v) {
    return __builtin_amdgcn_rcpf(1.f + __builtin_amdgcn_exp2f(-1.4426950408889634f * v));
}
__device__ __forceinline__ float tanh_(float v) {
    return 2.f * __builtin_amdgcn_rcpf(1.f + __builtin_amdgcn_exp2f(-2.8853900817779268f * v)) - 1.f;
}

#define SCHED0 __builtin_amdgcn_sched_barrier(0)

// ---------------- prologue kernels ----------------

__global__ void wc_kernel(const float* __restrict__ Wih1, const float* __restrict__ W_enc,
                          const float* __restrict__ b_enc, float* __restrict__ WC,
                          float* __restrict__ benc) {
    int i = blockIdx.x * 256 + threadIdx.x;
    if (i >= 1024 * 35) return;
    int j = i / 35;
    int f = i - j * 35;
    const float* wr = Wih1 + j * 256;
    float s = 0.f;
    if (f < 34) {
        for (int e = 0; e < 256; ++e) s += wr[e] * W_enc[e * 34 + f];
        WC[j * 34 + f] = s;
    } else {
        for (int e = 0; e < 256; ++e) s += wr[e] * b_enc[e];
        benc[j] = s;
    }
}

// Pack W (row-major [srcRows, srcK]) into per-wave-sequential bf16 B-frag streams:
// linear s16x8 index ((ntb*KK + kk)*G + g)*64 + lane holds
//   W[g*gStride + ntb*16 + (lane&15)][kk*32 + (lane>>4)*8 + j]  (0 outside bounds)
__global__ void pack_kernel(const float* __restrict__ src, unsigned short* __restrict__ dst,
                            int NTB, int KK, int G, int gStride, int srcRows, int srcK) {
    int idx = blockIdx.x * 256 + threadIdx.x;
    int total = NTB * KK * G * 64;
    if (idx >= total) return;
    int lane = idx & 63, q = idx >> 6;
    int g = q % G; q /= G;
    int kk = q % KK;
    int ntb = q / KK;
    int row = g * gStride + ntb * 16 + (lane & 15);
    int kbase = kk * 32 + ((lane >> 4) & 3) * 8;
    s16x8 v;
    #pragma unroll
    for (int j = 0; j < 8; ++j) {
        int k = kbase + j;
        float fv = (row < srcRows && k < srcK) ? src[row * srcK + k] : 0.f;
        v[j] = (short)f2bf(fv);
    }
    *(s16x8*)(dst + (long)idx * 8) = v;
}

__global__ void bias_kernel(const float* bih1, const float* bhh1, const float* benc,
                            const float* bih2, const float* bhh2, const float* b_dec,
                            float* bs1a, float* bs1b, float* bs2, float* bdec) {
    int j = blockIdx.x * 256 + threadIdx.x;
    if (j < 1024) {
        float s = bih1[j] + bhh1[j];
        bs1a[j] = s + benc[j];
        bs1b[j] = s;
        bs2[j] = bih2[j] + bhh2[j];
    }
    if (j < 48) bdec[j] = (j < 34) ? b_dec[j] : 0.f;
}

// ---------------- fused LSTM kernel ----------------
//
// Block = 256 threads (4 waves, 1 wave/SIMD -> 512 unified regs/wave).
// Each wave owns 4 ntb (wave*4..wave*4+3), processed as two s-pairs.
// Register plan per wave:
//   AGPR: acc[2][4][4] f32x4 = 128 + c1/c2 state 128 = 256 (full a-file)
//   arch: aC 32 + B double-buffer (2 bufs x 2 s x 4 frags) 128 + hp 32 + ptrs ~40
// B comes global->register directly (no LDS round-trip); compiler inserts exact
// vmcnt. A (activations) via LDS frag-linear layout (proven conflict-free):
//   block (u, mt) at base + (u*4+mt)*520 + lane*8  (shorts)
template<int KKIN>
__device__ __forceinline__ void cell_step(
    const unsigned short* Ain, const unsigned short* Ahid,
    const unsigned short* __restrict__ pWin,
    const unsigned short* __restrict__ pWhid,
    const float* Lbias, float (&cst)[2][2][4][4], unsigned short* Hout,
    int wave, int lane, int ln15, int quad) {
    constexpr int T = KKIN + 8;  // 10 or 16 (even)
    unsigned int hp[4][8];

    #pragma unroll
    for (int pr = 0; pr < 2; ++pr) {
        const int ntb0 = wave * 4 + pr * 2;
        const unsigned short* pIn  = pWin  + ntb0 * (KKIN * 2048);
        const unsigned short* pHid = pWhid + ntb0 * (8 * 2048);

        f32x4 acc[2][4][4];
        #pragma unroll
        for (int s = 0; s < 2; ++s)
            #pragma unroll
            for (int g = 0; g < 4; ++g)
                #pragma unroll
                for (int mt = 0; mt < 4; ++mt) acc[s][g][mt] = f32x4{0.f, 0.f, 0.f, 0.f};

        s16x8 aC[4], b00[4], b01[4], b10[4], b11[4];  // b{buf}{s}

        auto load8 = [&](int v, s16x8 (&bs0)[4], s16x8 (&bs1)[4]) {
            const unsigned short* p; int so;
            if (v < KKIN) { p = pIn + v * 2048; so = KKIN * 2048; }
            else          { p = pHid + (v - KKIN) * 2048; so = 8 * 2048; }
            #pragma unroll
            for (int g = 0; g < 4; ++g) {
                bs0[g] = *(const s16x8*)(p + g * 512 + lane * 8);
                bs1[g] = *(const s16x8*)(p + so + g * 512 + lane * 8);
            }
        };
        auto abase = [&](int v) -> const unsigned short* {
            return (v < KKIN) ? Ain + v * 2080 : Ahid + (v - KKIN) * 2080;
        };
        // One k-tile: 32 MFMA (2 s x 4 g x 4 mt), mt-outer; after aC[mt]'s last
        // use this tile, reload it from A(vnext) (-> ~3 mt-groups of latency cover).
        auto tile = [&](s16x8 (&bs0)[4], s16x8 (&bs1)[4], int vnext, bool rel) {
            const unsigned short* ap = abase(vnext);
            #pragma unroll
            for (int mt = 0; mt < 4; ++mt) {
                #pragma unroll
                for (int g = 0; g < 4; ++g) {
                    acc[0][g][mt] = MFMA(aC[mt], bs0[g], acc[0][g][mt]);
                    acc[1][g][mt] = MFMA(aC[mt], bs1[g], acc[1][g][mt]);
                }
                if (rel) aC[mt] = *(const s16x8*)(ap + mt * 520 + lane * 8);
                SCHED0;
            }
        };

        // prologue: B(0), B(1) in flight; aC = A(0)
        load8(0, b00, b01);
        load8(1, b10, b11);
        {
            const unsigned short* ap = abase(0);
            #pragma unroll
            for (int mt = 0; mt < 4; ++mt)
                aC[mt] = *(const s16x8*)(ap + mt * 520 + lane * 8);
        }
        #pragma unroll 1
        for (int u = 0; u <= T - 4; u += 2) {
            tile(b00, b01, u + 1, true);
            load8(u + 2, b00, b01);   // issue next-next tile while computing
            SCHED0;
            tile(b10, b11, u + 2, true);
            if (u + 3 < T) load8(u + 3, b10, b11);
            SCHED0;
        }
        tile(b00, b01, T - 1, true);   // tile T-2
        tile(b10, b11, 0, false);      // tile T-1 (no reload)

        #pragma unroll
        for (int s = 0; s < 2; ++s) {
            const int colB = (ntb0 + s) * 16 + ln15;
            const float bi = Lbias[colB], bff = Lbias[256 + colB];
            const float bg = Lbias[512 + colB], bo = Lbias[768 + colB];
            #pragma unroll
            for (int mt = 0; mt < 4; ++mt) {
                #pragma unroll
                for (int r = 0; r < 4; ++r) {
                    float iv = acc[s][0][mt][r] + bi;
                    float fv = acc[s][1][mt][r] + bff;
                    float gv = acc[s][2][mt][r] + bg;
                    float ov = acc[s][3][mt][r] + bo;
                    float cn = sigm(fv) * cst[pr][s][mt][r] + sigm(iv) * tanh_(gv);
                    cst[pr][s][mt][r] = cn;
                    float hv = sigm(ov) * tanh_(cn);
                    unsigned int hb = (unsigned int)f2bf(hv);
                    if ((r & 1) == 0) hp[pr * 2 + s][mt * 2 + (r >> 1)] = hb;
                    else              hp[pr * 2 + s][mt * 2 + (r >> 1)] |= (hb << 16);
                }
            }
        }
    }
    __syncthreads();  // all waves done reading h-buffers
    // scatter new h into frag-linear layout: ntb = wave*4+q;
    // element (row=mt*16+quad*4+r, col=ntb*16+ln15) -> block (ntb>>1, mt);
    // laneA = (quad*4+r) | ((((ntb&1)*16+ln15)>>3)<<4); j = ln15&7
    #pragma unroll
    for (int q = 0; q < 4; ++q) {
        const int ub = wave * 2 + (q >> 1);
        const int q16 = (q & 1) * 16 + ln15;
        #pragma unroll
        for (int mt = 0; mt < 4; ++mt)
            #pragma unroll
            for (int r = 0; r < 4; ++r)
                Hout[(ub * 4 + mt) * 520 + (quad * 4 + r) * 8 + (q16 >> 3) * 128 + (q16 & 7)] =
                    (unsigned short)(hp[q][mt * 2 + (r >> 1)] >> ((r & 1) * 16));
    }
    __syncthreads();  // new h visible
}

// LDS: h1f 33280 + h2f 33280 + scratch 12288 + Lb 12288 + Lbd 256 = 91392 B. 1 block/CU.
__global__ __launch_bounds__(256, 1) void lstm_fused(
    const float* __restrict__ x,
    const unsigned short* __restrict__ pWC,
    const unsigned short* __restrict__ pWih1,
    const unsigned short* __restrict__ pWhh1,
    const unsigned short* __restrict__ pWih2,
    const unsigned short* __restrict__ pWhh2,
    const unsigned short* __restrict__ pWdec,
    const float* __restrict__ gb1a, const float* __restrict__ gb1b,
    const float* __restrict__ gb2, const float* __restrict__ gbd,
    float* __restrict__ out) {
    extern __shared__ unsigned char smem[];
    unsigned short* h1f = (unsigned short*)smem;                  // 16640 shorts (8u x 4mt x 520)
    unsigned short* h2f = h1f + 16640;
    unsigned char* scratch = (unsigned char*)(h2f + 16640);       // 12288 B union:
    unsigned short* xfrag = (unsigned short*)scratch;             //   obs: 2u x 4mt x 520 = 8320 B
    float* dOut = (float*)scratch;                                //   dec: 64 x 48 f32 = 12288 B
    float* Lb1a = (float*)(scratch + 12288);
    float* Lb1b = Lb1a + 1024;
    float* Lb2  = Lb1b + 1024;
    float* Lbd  = Lb2 + 1024;                                     // 48 used (256 B)

    const int tid = threadIdx.x;
    const int wave = tid >> 6;
    const int lane = tid & 63;
    const int ln15 = lane & 15;
    const int quad = lane >> 4;
    const int m0 = blockIdx.x * 64;

    for (int i = tid; i < 16640; i += 256) ((int*)h1f)[i] = 0;    // h1f+h2f (contiguous)
    for (int i = tid; i < 3072; i += 256) ((int*)scratch)[i] = 0;
    for (int i = tid; i < 1024; i += 256) { Lb1a[i] = gb1a[i]; Lb1b[i] = gb1b[i]; Lb2[i] = gb2[i]; }
    if (tid < 48) Lbd[tid] = gbd[tid];

    float c1[2][2][4][4], c2[2][2][4][4];
    #pragma unroll
    for (int pr = 0; pr < 2; ++pr)
        #pragma unroll
        for (int s = 0; s < 2; ++s)
            #pragma unroll
            for (int mt = 0; mt < 4; ++mt)
                #pragma unroll
                for (int r = 0; r < 4; ++r) { c1[pr][s][mt][r] = 0.f; c2[pr][s][mt][r] = 0.f; }

    __syncthreads();

    #pragma unroll 1
    for (int t = 0; t < 19; ++t) {
        if (t < 10) {
            // stage x_t -> xfrag (bf16, fragment-linear; chunks for cols 34..63 stay zero)
            for (int i = tid; i < 1088; i += 256) {
                int r = i / 17, p = i - r * 17;
                int c = 2 * p;
                f32x2 v = __builtin_nontemporal_load((const f32x2*)(x + (m0 + r) * 340 + t * 34) + p);
                int u = c >> 5, mt = r >> 4;
                int laneA = (r & 15) | (((c >> 3) & 3) << 4);
                unsigned int packed = (unsigned int)f2bf(v.x) | ((unsigned int)f2bf(v.y) << 16);
                *(unsigned int*)(xfrag + (u * 4 + mt) * 520 + laneA * 8 + (c & 7)) = packed;
            }
            __syncthreads();
            cell_step<2>(xfrag, h1f, pWC, pWhh1, Lb1a, c1, h1f, wave, lane, ln15, quad);
        } else {
            cell_step<8>(h2f, h1f, pWih1, pWhh1, Lb1b, c1, h1f, wave, lane, ln15, quad);
        }
        cell_step<8>(h1f, h2f, pWih2, pWhh2, Lb2, c2, h2f, wave, lane, ln15, quad);

        if (t >= 9) {
            const int tout = t - 9;
            if (wave < 3) {  // decoder: dec = h2 @ W_dec^T + b_dec ; cumsum in dOut (LDS)
                f32x4 d[4];
                #pragma unroll
                for (int mt = 0; mt < 4; ++mt) d[mt] = f32x4{0.f, 0.f, 0.f, 0.f};
                #pragma unroll
                for (int kk = 0; kk < 8; ++kk) {
                    s16x8 b = *((const s16x8*)pWdec + (wave * 8 + kk) * 64 + lane);
                    #pragma unroll
                    for (int mt = 0; mt < 4; ++mt) {
                        s16x8 a = *(const s16x8*)(h2f + (kk * 4 + mt) * 520 + lane * 8);
                        d[mt] = MFMA(a, b, d[mt]);
                    }
                }
                const int col = wave * 16 + ln15;
                const bool valid = (col < 34);
                const float bd = Lbd[col];
                #pragma unroll
                for (int mt = 0; mt < 4; ++mt) {
                    #pragma unroll
                    for (int r = 0; r < 4; ++r) {
                        const int rloc = mt * 16 + quad * 4 + r;
                        float v = d[mt][r] + bd;
                        if (tout == 0) {
                            float xr = valid ? __builtin_nontemporal_load(x + (m0 + rloc) * 340 + 306 + col) : 0.f;
                            dOut[rloc * 48 + col] = v + xr;
                        } else {
                            dOut[rloc * 48 + col] += v;
                        }
                    }
                }
            }
            __syncthreads();
            // contiguous per-row non-temporal stores
            for (int i = tid; i < 1088; i += 256) {
                int r = i / 17, p = i - r * 17;
                f32x2 v = *(const f32x2*)(dOut + r * 48 + p * 2);
                __builtin_nontemporal_store(v, (f32x2*)(out + (m0 + r) * 340 + tout * 34) + p);
            }
            // no barrier needed: dOut is rewritten only after cell barriers of step t+1
        }
    }
}

// ---------------- launch ----------------

extern "C" void kernel_launch(void* const* d_in, const int* in_sizes, int n_in,
                              void* d_out, int out_size, void* d_ws, size_t ws_size,
                              hipStream_t stream) {
    const float* x     = (const float*)d_in[0];
    const float* W_enc = (const float*)d_in[1];
    const float* b_enc = (const float*)d_in[2];
    const float* Wih1  = (const float*)d_in[3];
    const float* Whh1  = (const float*)d_in[4];
    const float* bih1  = (const float*)d_in[5];
    const float* bhh1  = (const float*)d_in[6];
    const float* Wih2  = (const float*)d_in[7];
    const float* Whh2  = (const float*)d_in[8];
    const float* bih2  = (const float*)d_in[9];
    const float* bhh2  = (const float*)d_in[10];
    const float* W_dec = (const float*)d_in[11];
    const float* b_dec = (const float*)d_in[12];
    float* out = (float*)d_out;

    unsigned char* w = (unsigned char*)d_ws;
    float* WC   = (float*)(w + 0);         // 139264
    float* benc = (float*)(w + 139264);    // 4096
    float* bs1a = (float*)(w + 143360);
    float* bs1b = (float*)(w + 147456);
    float* bs2  = (float*)(w + 151552);
    float* bdec = (float*)(w + 155648);    // 256
    unsigned short* pWC   = (unsigned short*)(w + 155904);   // 131072
    unsigned short* pWih1 = (unsigned short*)(w + 286976);   // 524288 each
    unsigned short* pWhh1 = (unsigned short*)(w + 811264);
    unsigned short* pWih2 = (unsigned short*)(w + 1335552);
    unsigned short* pWhh2 = (unsigned short*)(w + 1859840);
    unsigned short* pWdec = (unsigned short*)(w + 2384128);  // 24576

    wc_kernel<<<140, 256, 0, stream>>>(Wih1, W_enc, b_enc, WC, benc);
    pack_kernel<<<32, 256, 0, stream>>>(WC, pWC, 16, 2, 4, 256, 1024, 34);
    pack_kernel<<<128, 256, 0, stream>>>(Wih1, pWih1, 16, 8, 4, 256, 1024, 256);
    pack_kernel<<<128, 256, 0, stream>>>(Whh1, pWhh1, 16, 8, 4, 256, 1024, 256);
    pack_kernel<<<128, 256, 0, stream>>>(Wih2, pWih2, 16, 8, 4, 256, 1024, 256);
    pack_kernel<<<128, 256, 0, stream>>>(Whh2, pWhh2, 16, 8, 4, 256, 1024, 256);
    pack_kernel<<<6, 256, 0, stream>>>(W_dec, pWdec, 3, 8, 1, 0, 34, 256);
    bias_kernel<<<4, 256, 0, stream>>>(bih1, bhh1, benc, bih2, bhh2, b_dec, bs1a, bs1b, bs2, bdec);

    hipFuncSetAttribute((const void*)lstm_fused, hipFuncAttributeMaxDynamicSharedMemorySize, 91392);
    lstm_fused<<<256, 256, 91392, stream>>>(x, pWC, pWih1, pWhh1, pWih2, pWhh2, pWdec,
                                            bs1a, bs1b, bs2, bdec, out);
}

// Round 7
// 1042.773 us; speedup vs baseline: 1.2762x; 1.2762x over previous
//
#include <hip/hip_runtime.h>

typedef float f32x4 __attribute__((ext_vector_type(4)));
typedef float f32x2 __attribute__((ext_vector_type(2)));
typedef short s16x8 __attribute__((ext_vector_type(8)));
typedef __bf16 bf16x8 __attribute__((ext_vector_type(8)));

__device__ __forceinline__ unsigned short f2bf(float f) {
    unsigned int u = __builtin_bit_cast(unsigned int, f);
    u += 0x7FFFu + ((u >> 16) & 1u);
    return (unsigned short)(u >> 16);
}

__device__ __forceinline__ f32x4 MFMA(s16x8 a, s16x8 b, f32x4 c) {
    return __builtin_amdgcn_mfma_f32_16x16x32_bf16(
        __builtin_bit_cast(bf16x8, a), __builtin_bit_cast(bf16x8, b), c, 0, 0, 0);
}

__device__ __forceinline__ float sigm(float v) {
    return __builtin_amdgcn_rcpf(1.f + __builtin_amdgcn_exp2f(-1.4426950408889634f * v));
}
__device__ __forceinline__ float tanh_(float v) {
    return 2.f * __builtin_amdgcn_rcpf(1.f + __builtin_amdgcn_exp2f(-2.8853900817779268f * v)) - 1.f;
}

// async global->LDS: per-lane global src (base + lane*16B), wave-uniform LDS base.
__device__ __forceinline__ void async_issue(const unsigned short* src, unsigned short* ldsDst,
                                            int lane) {
    __builtin_amdgcn_global_load_lds(
        (const __attribute__((address_space(1))) void*)(src + lane * 8),
        (__attribute__((address_space(3))) void*)ldsDst, 16, 0, 0);
}

#define VMCNT(n) asm volatile("s_waitcnt vmcnt(" #n ")" ::: "memory")
#define LGKM(n)  asm volatile("s_waitcnt lgkmcnt(" #n ")" ::: "memory")
#define SCHED0   __builtin_amdgcn_sched_barrier(0)

// ---------------- fused prologue kernel ----------------
// One launch replaces wc + 6x pack + bias (8-launch chain cost ~80us/iter).
// Inter-kernel dependency (WC, benc) broken by recomputing the dot products
// directly where consumed.
__global__ void prep_kernel(const float* __restrict__ W_enc, const float* __restrict__ b_enc,
                            const float* __restrict__ Wih1, const float* __restrict__ Whh1,
                            const float* __restrict__ Wih2, const float* __restrict__ Whh2,
                            const float* __restrict__ W_dec,
                            const float* __restrict__ bih1, const float* __restrict__ bhh1,
                            const float* __restrict__ bih2, const float* __restrict__ bhh2,
                            const float* __restrict__ b_dec,
                            unsigned short* __restrict__ pWC, unsigned short* __restrict__ pWih1,
                            unsigned short* __restrict__ pWhh1, unsigned short* __restrict__ pWih2,
                            unsigned short* __restrict__ pWhh2, unsigned short* __restrict__ pWdec,
                            float* __restrict__ bs1a, float* __restrict__ bs1b,
                            float* __restrict__ bs2, float* __restrict__ bdec) {
    const int bid = blockIdx.x;
    if (bid < 32) {
        // pack WC where WC = Wih1 @ W_enc^T (on the fly). NTB=16, KK=2, G=4, srcK=34.
        int idx = bid * 256 + threadIdx.x;            // < 8192 s16x8
        int lane = idx & 63, q = idx >> 6;
        int g = q & 3; q >>= 2;
        int kk = q & 1; q >>= 1;
        int ntb = q;
        int row = g * 256 + ntb * 16 + (lane & 15);   // < 1024 always
        int kbase = kk * 32 + ((lane >> 4) & 3) * 8;
        float acc8[8];
        #pragma unroll
        for (int j = 0; j < 8; ++j) acc8[j] = 0.f;
        const float* wr = Wih1 + row * 256;
        for (int e = 0; e < 256; ++e) {
            float w = wr[e];
            const float* we = W_enc + e * 34;
            #pragma unroll
            for (int j = 0; j < 8; ++j) {
                int k = kbase + j;
                if (k < 34) acc8[j] += w * we[k];
            }
        }
        s16x8 v;
        #pragma unroll
        for (int j = 0; j < 8; ++j) v[j] = (short)f2bf(acc8[j]);
        *(s16x8*)(pWC + (long)idx * 8) = v;
    } else if (bid < 544) {
        // pack one of Wih1/Whh1/Wih2/Whh2: NTB=16, KK=8, G=4 (128 blocks each)
        int m = (bid - 32) >> 7;
        int idx = ((bid - 32) & 127) * 256 + threadIdx.x;  // < 32768 s16x8
        const float* src = (m == 0) ? Wih1 : (m == 1) ? Whh1 : (m == 2) ? Wih2 : Whh2;
        unsigned short* dst = (m == 0) ? pWih1 : (m == 1) ? pWhh1 : (m == 2) ? pWih2 : pWhh2;
        int lane = idx & 63, q = idx >> 6;
        int g = q & 3; q >>= 2;
        int kk = q & 7; q >>= 3;
        int ntb = q;
        int row = g * 256 + ntb * 16 + (lane & 15);
        int kbase = kk * 32 + ((lane >> 4) & 3) * 8;
        s16x8 v;
        #pragma unroll
        for (int j = 0; j < 8; ++j) v[j] = (short)f2bf(src[row * 256 + kbase + j]);
        *(s16x8*)(dst + (long)idx * 8) = v;
    } else if (bid < 550) {
        // pack W_dec: NTB=3, KK=8, G=1; srcRows=34
        int idx = (bid - 544) * 256 + threadIdx.x;
        if (idx < 1536) {
            int lane = idx & 63, q = idx >> 6;
            int kk = q & 7;
            int ntb = q >> 3;
            int row = ntb * 16 + (lane & 15);
            int kbase = kk * 32 + ((lane >> 4) & 3) * 8;
            s16x8 v;
            #pragma unroll
            for (int j = 0; j < 8; ++j) {
                float fv = (row < 34) ? W_dec[row * 256 + kbase + j] : 0.f;
                v[j] = (short)f2bf(fv);
            }
            *(s16x8*)(pWdec + (long)idx * 8) = v;
        }
    } else {
        // bias: benc recomputed in place. blocks 550..553
        int j = (bid - 550) * 256 + threadIdx.x;      // < 1024
        float be = 0.f;
        const float* wr = Wih1 + j * 256;
        for (int e = 0; e < 256; ++e) be += wr[e] * b_enc[e];
        float s = bih1[j] + bhh1[j];
        bs1a[j] = s + be;
        bs1b[j] = s;
        bs2[j] = bih2[j] + bhh2[j];
        if (bid == 550 && threadIdx.x < 48)
            bdec[threadIdx.x] = (threadIdx.x < 34) ? b_dec[threadIdx.x] : 0.f;
    }
}

// ---------------- fused LSTM kernel ----------------
//
// A layout (frag-linear, conflict-free): block (u, mt) at
//   base + (u*4 + mt)*520 + lane*8  (shorts); element = Act[mt*16+(l&15)][u*32+(l>>4)*8+j].
//
// B streams through a per-wave 8-slot x 1KB LDS ring via async global_load_lds.
// Cross-cell pipeline: each cell's tail pre-issues the NEXT cell's first two
// B-tiles (nIn, nIn+2048) before the epilogue; they land during the ~2000cy
// epilogue + the __syncthreads vmcnt drain -> the next cell's prologue never
// stalls, and no VMCNT(0) hard drain exists anywhere in the loop.
// Per-tile VMCNT(4) sits after the first MFMA group (its first consumer is the
// b[0] after-use reload) -> ~75cy extra latency cover for free.
template<int KKIN>
__device__ __forceinline__ void cell_step(
    const unsigned short* Ain,   // frag-linear (tile u at +u*2080)
    const unsigned short* Ahid,
    const unsigned short* __restrict__ pWin,
    const unsigned short* __restrict__ pWhid,
    const unsigned short* __restrict__ nIn,   // next cell's first-B base (this wave)
    const float* Lbias, float (&cst)[2][4][4], unsigned short* Hout,
    unsigned short* Bst, int wave, int lane, int ln15, int quad) {
    constexpr int T = KKIN + 8;  // 10 or 16 (even)
    unsigned int hp[2][8];
    const int wv2 = wave * 2;

    auto bsrc = [&](int v) -> const unsigned short* {  // v in [0, 2T)
        int ss = (v >= T) ? 1 : 0;
        int u = v - ss * T;
        int ntb = wv2 + ss;
        return (u < KKIN) ? pWin + (ntb * KKIN + u) * 2048
                          : pWhid + (ntb * 8 + (u - KKIN)) * 2048;
    };
    auto asrc = [&](int v) -> const unsigned short* {
        int u = (v >= T) ? v - T : v;
        return (u < KKIN) ? Ain + u * 2080 : Ahid + (u - KKIN) * 2080;
    };
    auto issue4 = [&](const unsigned short* src, int so) {
        async_issue(src,        Bst + so,        lane);
        async_issue(src + 512,  Bst + so + 512,  lane);
        async_issue(src + 1024, Bst + so + 1024, lane);
        async_issue(src + 1536, Bst + so + 1536, lane);
    };
    auto readA = [&](const unsigned short* ab, s16x8 (&a)[4]) {
        #pragma unroll
        for (int mt = 0; mt < 4; ++mt)
            a[mt] = *(const s16x8*)(ab + mt * 520 + lane * 8);
    };

    s16x8 aC[4], aN[4], b[4];
    f32x4 acc[4][4];

    // prologue: B(0)/B(1) were pre-issued by the previous cell (or the kernel
    // preamble) and drained at the barrier -> slots are valid, no stall.
    VMCNT(4);
    readA(asrc(0), aC);
    #pragma unroll
    for (int g = 0; g < 4; ++g)
        b[g] = *(const s16x8*)(Bst + g * 512 + lane * 8);

    #pragma unroll
    for (int s = 0; s < 2; ++s) {
        #pragma unroll
        for (int g = 0; g < 4; ++g)
            #pragma unroll
            for (int mt = 0; mt < 4; ++mt) acc[g][mt] = f32x4{0.f, 0.f, 0.f, 0.f};
        const int base = s * T;
        const int nrm = s ? (T - 2) : T;  // s=1: last 2 tiles peeled (drain)
        #pragma unroll 1
        for (int u = 0; u < nrm; u += 2) {
            const int v = base + u;  // even
            // even tile v: use aC, fill aN; issue -> slots0; reload b <- slots4 (B(v+1))
            readA(asrc(v + 1), aN);
            LGKM(4);
            issue4(bsrc(v + 2), 0);
            acc[0][0] = MFMA(aC[0], b[0], acc[0][0]);
            acc[0][1] = MFMA(aC[1], b[0], acc[0][1]);
            acc[0][2] = MFMA(aC[2], b[0], acc[0][2]);
            acc[0][3] = MFMA(aC[3], b[0], acc[0][3]);
            VMCNT(4);  // B(v+1) landed (only B(v+2) outstanding)
            b[0] = *(const s16x8*)(Bst + 2048 + lane * 8);
            SCHED0;
            #pragma unroll
            for (int g = 1; g < 4; ++g) {
                acc[g][0] = MFMA(aC[0], b[g], acc[g][0]);
                acc[g][1] = MFMA(aC[1], b[g], acc[g][1]);
                acc[g][2] = MFMA(aC[2], b[g], acc[g][2]);
                acc[g][3] = MFMA(aC[3], b[g], acc[g][3]);
                b[g] = *(const s16x8*)(Bst + 2048 + g * 512 + lane * 8);
                SCHED0;
            }
            // odd tile v+1: use aN, fill aC; issue -> slots4; reload b <- slots0 (B(v+2))
            readA(asrc(v + 2), aC);
            LGKM(4);
            issue4(bsrc(v + 3), 2048);
            acc[0][0] = MFMA(aN[0], b[0], acc[0][0]);
            acc[0][1] = MFMA(aN[1], b[0], acc[0][1]);
            acc[0][2] = MFMA(aN[2], b[0], acc[0][2]);
            acc[0][3] = MFMA(aN[3], b[0], acc[0][3]);
            VMCNT(4);  // B(v+2) landed
            b[0] = *(const s16x8*)(Bst + lane * 8);
            SCHED0;
            #pragma unroll
            for (int g = 1; g < 4; ++g) {
                acc[g][0] = MFMA(aN[0], b[g], acc[g][0]);
                acc[g][1] = MFMA(aN[1], b[g], acc[g][1]);
                acc[g][2] = MFMA(aN[2], b[g], acc[g][2]);
                acc[g][3] = MFMA(aN[3], b[g], acc[g][3]);
                b[g] = *(const s16x8*)(Bst + g * 512 + lane * 8);
                SCHED0;
            }
        }
        if (s == 1) {
            // tail tile 2T-2 (aC): pre-issue next cell's B(0) into slots0
            readA(asrc(2 * T - 1), aN);
            LGKM(4);
            issue4(nIn, 0);
            acc[0][0] = MFMA(aC[0], b[0], acc[0][0]);
            acc[0][1] = MFMA(aC[1], b[0], acc[0][1]);
            acc[0][2] = MFMA(aC[2], b[0], acc[0][2]);
            acc[0][3] = MFMA(aC[3], b[0], acc[0][3]);
            VMCNT(4);  // B(2T-1) landed (only nIn's 4 outstanding)
            b[0] = *(const s16x8*)(Bst + 2048 + lane * 8);
            SCHED0;
            #pragma unroll
            for (int g = 1; g < 4; ++g) {
                acc[g][0] = MFMA(aC[0], b[g], acc[g][0]);
                acc[g][1] = MFMA(aC[1], b[g], acc[g][1]);
                acc[g][2] = MFMA(aC[2], b[g], acc[g][2]);
                acc[g][3] = MFMA(aC[3], b[g], acc[g][3]);
                b[g] = *(const s16x8*)(Bst + 2048 + g * 512 + lane * 8);
                SCHED0;
            }
            // tail tile 2T-1 (aN): pure MFMA drain, then pre-issue next B(1)
            #pragma unroll
            for (int g = 0; g < 4; ++g) {
                acc[g][0] = MFMA(aN[0], b[g], acc[g][0]);
                acc[g][1] = MFMA(aN[1], b[g], acc[g][1]);
                acc[g][2] = MFMA(aN[2], b[g], acc[g][2]);
                acc[g][3] = MFMA(aN[3], b[g], acc[g][3]);
            }
            LGKM(0);                    // slots4 reads retired (long done)
            issue4(nIn + 2048, 2048);   // next cell B(1) -> slots4; lands during epilogue
        }

        const int colB = (wv2 + s) * 16 + ln15;
        const float bi = Lbias[colB], bff = Lbias[256 + colB];
        const float bg = Lbias[512 + colB], bo = Lbias[768 + colB];
        #pragma unroll
        for (int mt = 0; mt < 4; ++mt) {
            #pragma unroll
            for (int r = 0; r < 4; ++r) {
                float iv = acc[0][mt][r] + bi;
                float fv = acc[1][mt][r] + bff;
                float gv = acc[2][mt][r] + bg;
                float ov = acc[3][mt][r] + bo;
                float cn = sigm(fv) * cst[s][mt][r] + sigm(iv) * tanh_(gv);
                cst[s][mt][r] = cn;
                float hv = sigm(ov) * tanh_(cn);
                unsigned int hb = (unsigned int)f2bf(hv);
                if ((r & 1) == 0) hp[s][mt * 2 + (r >> 1)] = hb;
                else              hp[s][mt * 2 + (r >> 1)] |= (hb << 16);
            }
        }
    }
    __syncthreads();  // all waves done reading h-buffers (also drains pre-issued loads)
    // scatter new h into frag-linear layout:
    // element (row=mt*16+quad*4+r, col=(2*wave+s)*16+ln15) ->
    //   block (u=wave, mt); laneA=(quad*4+r) | ((2s+(ln15>>3))<<4); j=ln15&7
    #pragma unroll
    for (int s = 0; s < 2; ++s)
        #pragma unroll
        for (int mt = 0; mt < 4; ++mt)
            #pragma unroll
            for (int r = 0; r < 4; ++r)
                Hout[(wave * 4 + mt) * 520 + (quad * 4 + r) * 8 +
                     (2 * s + (ln15 >> 3)) * 128 + (ln15 & 7)] =
                    (unsigned short)(hp[s][mt * 2 + (r >> 1)] >> ((r & 1) * 16));
    __syncthreads();  // new h visible
}

// LDS: h1f 33280 + h2f 33280 + scratch 12288 + Lb 12288 + Lbd 256 + Bring 65536 = 156928 B.
__global__ __launch_bounds__(512, 2) void lstm_fused(
    const float* __restrict__ x,
    const unsigned short* __restrict__ pWC,
    const unsigned short* __restrict__ pWih1,
    const unsigned short* __restrict__ pWhh1,
    const unsigned short* __restrict__ pWih2,
    const unsigned short* __restrict__ pWhh2,
    const unsigned short* __restrict__ pWdec,
    const float* __restrict__ gb1a, const float* __restrict__ gb1b,
    const float* __restrict__ gb2, const float* __restrict__ gbd,
    float* __restrict__ out) {
    extern __shared__ unsigned char smem[];
    unsigned short* h1f = (unsigned short*)smem;                  // 16640 shorts (8u x 4mt x 520)
    unsigned short* h2f = h1f + 16640;
    unsigned char* scratch = (unsigned char*)(h2f + 16640);       // 12288 B union:
    unsigned short* xfrag = (unsigned short*)scratch;             //   obs: 2u x 4mt x 520 = 8320 B
    float* dOut = (float*)scratch;                                //   dec: 64 x 48 f32 = 12288 B
    float* Lb1a = (float*)(scratch + 12288);
    float* Lb1b = Lb1a + 1024;
    float* Lb2  = Lb1b + 1024;
    float* Lbd  = Lb2 + 1024;                                     // 48 used (256 B)
    unsigned short* Bring = (unsigned short*)(scratch + 12288 + 12288 + 256);  // 65536 B

    const int tid = threadIdx.x;
    const int wave = tid >> 6;
    const int lane = tid & 63;
    const int ln15 = lane & 15;
    const int quad = lane >> 4;
    const int m0 = blockIdx.x * 64;
    unsigned short* Bst = Bring + wave * 4096;  // this wave's 8KB (8 slots x 1KB)

    // next-cell first-B bases for this wave (bsrc(0) with ntb = wave*2)
    const unsigned short* nWC   = pWC   + wave * 2 * (2 * 2048);
    const unsigned short* nWih1 = pWih1 + wave * 2 * (8 * 2048);
    const unsigned short* nWih2 = pWih2 + wave * 2 * (8 * 2048);

    // preamble: issue the very first cell's B(0)/B(1); they drain at the init barrier.
    {
        async_issue(nWC,        Bst + 0,    lane);
        async_issue(nWC + 512,  Bst + 512,  lane);
        async_issue(nWC + 1024, Bst + 1024, lane);
        async_issue(nWC + 1536, Bst + 1536, lane);
        async_issue(nWC + 2048, Bst + 2048, lane);
        async_issue(nWC + 2560, Bst + 2560, lane);
        async_issue(nWC + 3072, Bst + 3072, lane);
        async_issue(nWC + 3584, Bst + 3584, lane);
    }

    for (int i = tid; i < 16640; i += 512) ((int*)h1f)[i] = 0;    // h1f+h2f (contiguous)
    for (int i = tid; i < 3072; i += 512) ((int*)scratch)[i] = 0;
    for (int i = tid; i < 1024; i += 512) { Lb1a[i] = gb1a[i]; Lb1b[i] = gb1b[i]; Lb2[i] = gb2[i]; }
    if (tid < 48) Lbd[tid] = gbd[tid];

    float c1[2][4][4], c2[2][4][4];
    #pragma unroll
    for (int s = 0; s < 2; ++s)
        #pragma unroll
        for (int mt = 0; mt < 4; ++mt)
            #pragma unroll
            for (int r = 0; r < 4; ++r) { c1[s][mt][r] = 0.f; c2[s][mt][r] = 0.f; }

    __syncthreads();

    #pragma unroll 1
    for (int t = 0; t < 19; ++t) {
        // layer1's successor is layer2; layer2's successor is layer1 of t+1
        const unsigned short* nAfter1 = nWih2;
        const unsigned short* nAfter2 = (t + 1 < 10) ? nWC : nWih1;  // t=18: dummy (never read)

        if (t < 10) {
            // stage x_t -> xfrag (bf16, fragment-linear; chunks for cols 34..63 stay zero)
            for (int i = tid; i < 1088; i += 512) {
                int r = i / 17, p = i - r * 17;
                int c = 2 * p;
                f32x2 v = __builtin_nontemporal_load((const f32x2*)(x + (m0 + r) * 340 + t * 34) + p);
                int u = c >> 5, mt = r >> 4;
                int laneA = (r & 15) | (((c >> 3) & 3) << 4);
                unsigned int packed = (unsigned int)f2bf(v.x) | ((unsigned int)f2bf(v.y) << 16);
                *(unsigned int*)(xfrag + (u * 4 + mt) * 520 + laneA * 8 + (c & 7)) = packed;
            }
            __syncthreads();
            cell_step<2>(xfrag, h1f, pWC, pWhh1, nAfter1, Lb1a, c1, h1f, Bst, wave, lane, ln15, quad);
        } else {
            cell_step<8>(h2f, h1f, pWih1, pWhh1, nAfter1, Lb1b, c1, h1f, Bst, wave, lane, ln15, quad);
        }
        cell_step<8>(h1f, h2f, pWih2, pWhh2, nAfter2, Lb2, c2, h2f, Bst, wave, lane, ln15, quad);

        if (t >= 9) {
            const int tout = t - 9;
            if (wave < 3) {  // decoder: dec = h2 @ W_dec^T + b_dec ; cumsum in dOut (LDS)
                f32x4 d[4];
                #pragma unroll
                for (int mt = 0; mt < 4; ++mt) d[mt] = f32x4{0.f, 0.f, 0.f, 0.f};
                #pragma unroll
                for (int kk = 0; kk < 8; ++kk) {
                    s16x8 b = *((const s16x8*)pWdec + (wave * 8 + kk) * 64 + lane);
                    #pragma unroll
                    for (int mt = 0; mt < 4; ++mt) {
                        s16x8 a = *(const s16x8*)(h2f + (kk * 4 + mt) * 520 + lane * 8);
                        d[mt] = MFMA(a, b, d[mt]);
                    }
                }
                const int col = wave * 16 + ln15;
                const bool valid = (col < 34);
                const float bd = Lbd[col];
                #pragma unroll
                for (int mt = 0; mt < 4; ++mt) {
                    #pragma unroll
                    for (int r = 0; r < 4; ++r) {
                        const int rloc = mt * 16 + quad * 4 + r;
                        float v = d[mt][r] + bd;
                        if (tout == 0) {
                            float xr = valid ? __builtin_nontemporal_load(x + (m0 + rloc) * 340 + 306 + col) : 0.f;
                            dOut[rloc * 48 + col] = v + xr;
                        } else {
                            dOut[rloc * 48 + col] += v;
                        }
                    }
                }
            }
            __syncthreads();
            // contiguous per-row non-temporal stores
            for (int i = tid; i < 1088; i += 512) {
                int r = i / 17, p = i - r * 17;
                f32x2 v = *(const f32x2*)(dOut + r * 48 + p * 2);
                __builtin_nontemporal_store(v, (f32x2*)(out + (m0 + r) * 340 + tout * 34) + p);
            }
            // no barrier needed: dOut is rewritten only after cell barriers of step t+1
        }
    }
}

// ---------------- launch ----------------

extern "C" void kernel_launch(void* const* d_in, const int* in_sizes, int n_in,
                              void* d_out, int out_size, void* d_ws, size_t ws_size,
                              hipStream_t stream) {
    const float* x     = (const float*)d_in[0];
    const float* W_enc = (const float*)d_in[1];
    const float* b_enc = (const float*)d_in[2];
    const float* Wih1  = (const float*)d_in[3];
    const float* Whh1  = (const float*)d_in[4];
    const float* bih1  = (const float*)d_in[5];
    const float* bhh1  = (const float*)d_in[6];
    const float* Wih2  = (const float*)d_in[7];
    const float* Whh2  = (const float*)d_in[8];
    const float* bih2  = (const float*)d_in[9];
    const float* bhh2  = (const float*)d_in[10];
    const float* W_dec = (const float*)d_in[11];
    const float* b_dec = (const float*)d_in[12];
    float* out = (float*)d_out;

    unsigned char* w = (unsigned char*)d_ws;
    float* bs1a = (float*)(w + 143360);
    float* bs1b = (float*)(w + 147456);
    float* bs2  = (float*)(w + 151552);
    float* bdec = (float*)(w + 155648);    // 256
    unsigned short* pWC   = (unsigned short*)(w + 155904);   // 131072
    unsigned short* pWih1 = (unsigned short*)(w + 286976);   // 524288 each
    unsigned short* pWhh1 = (unsigned short*)(w + 811264);
    unsigned short* pWih2 = (unsigned short*)(w + 1335552);
    unsigned short* pWhh2 = (unsigned short*)(w + 1859840);
    unsigned short* pWdec = (unsigned short*)(w + 2384128);  // 24576

    prep_kernel<<<554, 256, 0, stream>>>(W_enc, b_enc, Wih1, Whh1, Wih2, Whh2, W_dec,
                                         bih1, bhh1, bih2, bhh2, b_dec,
                                         pWC, pWih1, pWhh1, pWih2, pWhh2, pWdec,
                                         bs1a, bs1b, bs2, bdec);

    hipFuncSetAttribute((const void*)lstm_fused, hipFuncAttributeMaxDynamicSharedMemorySize, 156928);
    lstm_fused<<<256, 512, 156928, stream>>>(x, pWC, pWih1, pWhh1, pWih2, pWhh2, pWdec,
                                             bs1a, bs1b, bs2, bdec, out);
}

// Round 8
// 712.429 us; speedup vs baseline: 1.8679x; 1.4637x over previous
//
#include <hip/hip_runtime.h>

typedef float f32x4 __attribute__((ext_vector_type(4)));
typedef float f32x2 __attribute__((ext_vector_type(2)));
typedef short s16x8 __attribute__((ext_vector_type(8)));
typedef __bf16 bf16x8 __attribute__((ext_vector_type(8)));

__device__ __forceinline__ unsigned short f2bf(float f) {
    unsigned int u = __builtin_bit_cast(unsigned int, f);
    u += 0x7FFFu + ((u >> 16) & 1u);
    return (unsigned short)(u >> 16);
}

__device__ __forceinline__ f32x4 MFMA(s16x8 a, s16x8 b, f32x4 c) {
    return __builtin_amdgcn_mfma_f32_16x16x32_bf16(
        __builtin_bit_cast(bf16x8, a), __builtin_bit_cast(bf16x8, b), c, 0, 0, 0);
}

__device__ __forceinline__ float sigm(float v) {
    return __builtin_amdgcn_rcpf(1.f + __builtin_amdgcn_exp2f(-1.4426950408889634f * v));
}
__device__ __forceinline__ float tanh_(float v) {
    return 2.f * __builtin_amdgcn_rcpf(1.f + __builtin_amdgcn_exp2f(-2.8853900817779268f * v)) - 1.f;
}

#define SCHED0 __builtin_amdgcn_sched_barrier(0)

// ---------------- prologue kernels (R5 proven config) ----------------

__global__ void wc_kernel(const float* __restrict__ Wih1, const float* __restrict__ W_enc,
                          const float* __restrict__ b_enc, float* __restrict__ WC,
                          float* __restrict__ benc) {
    int i = blockIdx.x * 256 + threadIdx.x;
    if (i >= 1024 * 35) return;
    int j = i / 35;
    int f = i - j * 35;
    const float* wr = Wih1 + j * 256;
    float s = 0.f;
    if (f < 34) {
        for (int e = 0; e < 256; ++e) s += wr[e] * W_enc[e * 34 + f];
        WC[j * 34 + f] = s;
    } else {
        for (int e = 0; e < 256; ++e) s += wr[e] * b_enc[e];
        benc[j] = s;
    }
}

// Pack W (row-major [srcRows, srcK]) into per-wave-sequential bf16 B-frag streams:
// linear s16x8 index ((ntb*KK + kk)*G + g)*64 + lane holds
//   W[g*gStride + ntb*16 + (lane&15)][kk*32 + (lane>>4)*8 + j]  (0 outside bounds)
__global__ void pack_kernel(const float* __restrict__ src, unsigned short* __restrict__ dst,
                            int NTB, int KK, int G, int gStride, int srcRows, int srcK) {
    int idx = blockIdx.x * 256 + threadIdx.x;
    int total = NTB * KK * G * 64;
    if (idx >= total) return;
    int lane = idx & 63, q = idx >> 6;
    int g = q % G; q /= G;
    int kk = q % KK;
    int ntb = q / KK;
    int row = g * gStride + ntb * 16 + (lane & 15);
    int kbase = kk * 32 + ((lane >> 4) & 3) * 8;
    s16x8 v;
    #pragma unroll
    for (int j = 0; j < 8; ++j) {
        int k = kbase + j;
        float fv = (row < srcRows && k < srcK) ? src[row * srcK + k] : 0.f;
        v[j] = (short)f2bf(fv);
    }
    *(s16x8*)(dst + (long)idx * 8) = v;
}

__global__ void bias_kernel(const float* bih1, const float* bhh1, const float* benc,
                            const float* bih2, const float* bhh2, const float* b_dec,
                            float* bs1a, float* bs1b, float* bs2, float* bdec) {
    int j = blockIdx.x * 256 + threadIdx.x;
    if (j < 1024) {
        float s = bih1[j] + bhh1[j];
        bs1a[j] = s + benc[j];
        bs1b[j] = s;
        bs2[j] = bih2[j] + bhh2[j];
    }
    if (j < 48) bdec[j] = (j < 34) ? b_dec[j] : 0.f;
}

// ---------------- fused LSTM kernel ----------------
//
// A layout (frag-linear, conflict-free): block (u, mt) at
//   base + (u*4 + mt)*520 + lane*8  (shorts); element = Act[mt*16+(l&15)][u*32+(l>>4)*8+j].
//
// R8 structure: B streams GLOBAL -> REGISTERS (no LDS round-trip; cuts per-cell
// LDS traffic 2.5MB -> 0.5MB). b0/b1 double-buffer: tile v consumes buf (v&1),
// then reloads that buffer with W(v+2) -> one full tile of load cover. All loads
// are register-dependent so the compiler inserts exact counted s_waitcnt.
// A single-buffered with per-mt after-use reload (~3 mt-groups + boundary of
// LDS cover). h double-buffered in LDS -> Hout aliases NO read buffer -> h
// written inline per-s, ONE barrier per cell_step, no hp registers.
// Register plan/wave: arch = a 32 + b0 32 + b1 32 + addr ~25 < 128;
// AGPR = acc 64 + c1 32 + c2 32 = 128.  Total 256 = 2 waves/SIMD budget.

template<bool DO_A, bool DO_W>
__device__ __forceinline__ void tile_op(s16x8 (&a)[4], s16x8 (&bb)[4], f32x4 (&acc)[4][4],
                                        const unsigned short* aNext,
                                        const unsigned short* wNext, int lane) {
    #pragma unroll
    for (int mt = 0; mt < 4; ++mt) {
        acc[0][mt] = MFMA(a[mt], bb[0], acc[0][mt]);
        acc[1][mt] = MFMA(a[mt], bb[1], acc[1][mt]);
        acc[2][mt] = MFMA(a[mt], bb[2], acc[2][mt]);
        acc[3][mt] = MFMA(a[mt], bb[3], acc[3][mt]);
        if constexpr (DO_A) a[mt] = *(const s16x8*)(aNext + mt * 520 + lane * 8);
        SCHED0;
    }
    if constexpr (DO_W) {
        bb[0] = *(const s16x8*)(wNext + lane * 8);
        bb[1] = *(const s16x8*)(wNext + 512 + lane * 8);
        bb[2] = *(const s16x8*)(wNext + 1024 + lane * 8);
        bb[3] = *(const s16x8*)(wNext + 1536 + lane * 8);
    }
    SCHED0;
}

template<int KKIN>
__device__ __forceinline__ void cell_step(
    const unsigned short* Ain,   // frag-linear (tile u at +u*2080)
    const unsigned short* Ahid,
    const unsigned short* __restrict__ pWin,
    const unsigned short* __restrict__ pWhid,
    const float* Lbias, float (&cst)[2][4][4], unsigned short* Hout,
    int wave, int lane, int ln15, int quad) {
    constexpr int T = KKIN + 8;  // 10 or 16 (even)
    const int wv2 = wave * 2;

    auto bsrc = [&](int v) -> const unsigned short* {  // v in [0, 2T)
        int ss = (v >= T) ? 1 : 0;
        int u = v - ss * T;
        int ntb = wv2 + ss;
        return (u < KKIN) ? pWin + (ntb * KKIN + u) * 2048
                          : pWhid + (ntb * 8 + (u - KKIN)) * 2048;
    };
    auto asrc = [&](int v) -> const unsigned short* {
        int u = (v >= T) ? v - T : v;
        return (u < KKIN) ? Ain + u * 2080 : Ahid + (u - KKIN) * 2080;
    };

    s16x8 a[4], b0[4], b1[4];
    f32x4 acc[4][4];

    // prologue: W(0)->b0, W(1)->b1 in flight; a = A(0)
    {
        const unsigned short* p0 = bsrc(0);
        const unsigned short* p1 = bsrc(1);
        b0[0] = *(const s16x8*)(p0 + lane * 8);
        b0[1] = *(const s16x8*)(p0 + 512 + lane * 8);
        b0[2] = *(const s16x8*)(p0 + 1024 + lane * 8);
        b0[3] = *(const s16x8*)(p0 + 1536 + lane * 8);
        b1[0] = *(const s16x8*)(p1 + lane * 8);
        b1[1] = *(const s16x8*)(p1 + 512 + lane * 8);
        b1[2] = *(const s16x8*)(p1 + 1024 + lane * 8);
        b1[3] = *(const s16x8*)(p1 + 1536 + lane * 8);
        const unsigned short* ap = asrc(0);
        #pragma unroll
        for (int mt = 0; mt < 4; ++mt)
            a[mt] = *(const s16x8*)(ap + mt * 520 + lane * 8);
    }

    #pragma unroll
    for (int s = 0; s < 2; ++s) {
        #pragma unroll
        for (int g = 0; g < 4; ++g)
            #pragma unroll
            for (int mt = 0; mt < 4; ++mt) acc[g][mt] = f32x4{0.f, 0.f, 0.f, 0.f};
        const int base = s * T;
        const int nrm = s ? (T - 2) : T;  // s=1: last pair peeled (drain)
        #pragma unroll 1
        for (int u = 0; u < nrm; u += 2) {
            const int v = base + u;  // even
            tile_op<true, true>(a, b0, acc, asrc(v + 1), bsrc(v + 2), lane);
            tile_op<true, true>(a, b1, acc, asrc(v + 2), bsrc(v + 3), lane);
        }
        if (s == 1) {
            tile_op<true, false>(a, b0, acc, asrc(2 * T - 1), nullptr, lane);
            tile_op<false, false>(a, b1, acc, nullptr, nullptr, lane);
        }

        // epilogue for column-stream s: gates -> c,h; h written inline (Hout is
        // the parity buffer nobody reads this step).
        const int colB = (wv2 + s) * 16 + ln15;
        const float bi = Lbias[colB], bff = Lbias[256 + colB];
        const float bg = Lbias[512 + colB], bo = Lbias[768 + colB];
        #pragma unroll
        for (int mt = 0; mt < 4; ++mt) {
            #pragma unroll
            for (int r = 0; r < 4; ++r) {
                float iv = acc[0][mt][r] + bi;
                float fv = acc[1][mt][r] + bff;
                float gv = acc[2][mt][r] + bg;
                float ov = acc[3][mt][r] + bo;
                float cn = sigm(fv) * cst[s][mt][r] + sigm(iv) * tanh_(gv);
                cst[s][mt][r] = cn;
                float hv = sigm(ov) * tanh_(cn);
                // frag-linear scatter: row=mt*16+quad*4+r, col=colB
                Hout[(wave * 4 + mt) * 520 + (quad * 4 + r) * 8 +
                     (2 * s + (ln15 >> 3)) * 128 + (ln15 & 7)] = f2bf(hv);
            }
        }
    }
    __syncthreads();  // publish new h (single barrier per cell)
}

// LDS: h1f[2] + h2f[2] (4 x 33280) + scratch 12288 + Lb 12288 + Lbd 256 = 157952 B.
__global__ __launch_bounds__(512, 1) void lstm_fused(
    const float* __restrict__ x,
    const unsigned short* __restrict__ pWC,
    const unsigned short* __restrict__ pWih1,
    const unsigned short* __restrict__ pWhh1,
    const unsigned short* __restrict__ pWih2,
    const unsigned short* __restrict__ pWhh2,
    const unsigned short* __restrict__ pWdec,
    const float* __restrict__ gb1a, const float* __restrict__ gb1b,
    const float* __restrict__ gb2, const float* __restrict__ gbd,
    float* __restrict__ out) {
    extern __shared__ unsigned char smem[];
    unsigned short* h1lo = (unsigned short*)smem;                 // 16640 shorts each
    unsigned short* h1hi = h1lo + 16640;
    unsigned short* h2lo = h1hi + 16640;
    unsigned short* h2hi = h2lo + 16640;
    unsigned char* scratch = (unsigned char*)(h2hi + 16640);      // 12288 B union:
    unsigned short* xfrag = (unsigned short*)scratch;             //   obs: 2u x 4mt x 520
    float* dOut = (float*)scratch;                                //   dec: 64 x 48 f32
    float* Lb1a = (float*)(scratch + 12288);
    float* Lb1b = Lb1a + 1024;
    float* Lb2  = Lb1b + 1024;
    float* Lbd  = Lb2 + 1024;                                     // 48 used (256 B)

    const int tid = threadIdx.x;
    const int wave = tid >> 6;
    const int lane = tid & 63;
    const int ln15 = lane & 15;
    const int quad = lane >> 4;
    const int m0 = blockIdx.x * 64;

    for (int i = tid; i < 33280; i += 512) ((int*)h1lo)[i] = 0;   // all 4 h buffers
    for (int i = tid; i < 3072; i += 512) ((int*)scratch)[i] = 0;
    for (int i = tid; i < 1024; i += 512) { Lb1a[i] = gb1a[i]; Lb1b[i] = gb1b[i]; Lb2[i] = gb2[i]; }
    if (tid < 48) Lbd[tid] = gbd[tid];

    float c1[2][4][4], c2[2][4][4];
    #pragma unroll
    for (int s = 0; s < 2; ++s)
        #pragma unroll
        for (int mt = 0; mt < 4; ++mt)
            #pragma unroll
            for (int r = 0; r < 4; ++r) { c1[s][mt][r] = 0.f; c2[s][mt][r] = 0.f; }

    __syncthreads();

    #pragma unroll 1
    for (int t = 0; t < 19; ++t) {
        const int cur = t & 1;
        unsigned short* h1r = cur ? h1hi : h1lo;
        unsigned short* h1w = cur ? h1lo : h1hi;
        unsigned short* h2r = cur ? h2hi : h2lo;
        unsigned short* h2w = cur ? h2lo : h2hi;

        if (t < 10) {
            // stage x_t -> xfrag (bf16, fragment-linear; chunks for cols 34..63 stay zero)
            for (int i = tid; i < 1088; i += 512) {
                int r = i / 17, p = i - r * 17;
                int c = 2 * p;
                f32x2 v = __builtin_nontemporal_load((const f32x2*)(x + (m0 + r) * 340 + t * 34) + p);
                int u = c >> 5, mt = r >> 4;
                int laneA = (r & 15) | (((c >> 3) & 3) << 4);
                unsigned int packed = (unsigned int)f2bf(v.x) | ((unsigned int)f2bf(v.y) << 16);
                *(unsigned int*)(xfrag + (u * 4 + mt) * 520 + laneA * 8 + (c & 7)) = packed;
            }
            __syncthreads();
            cell_step<2>(xfrag, h1r, pWC, pWhh1, Lb1a, c1, h1w, wave, lane, ln15, quad);
        } else {
            cell_step<8>(h2r, h1r, pWih1, pWhh1, Lb1b, c1, h1w, wave, lane, ln15, quad);
        }
        cell_step<8>(h1w, h2r, pWih2, pWhh2, Lb2, c2, h2w, wave, lane, ln15, quad);

        if (t >= 9) {
            const int tout = t - 9;
            if (wave < 3) {  // decoder: dec = h2 @ W_dec^T + b_dec ; cumsum in dOut (LDS)
                f32x4 d[4];
                #pragma unroll
                for (int mt = 0; mt < 4; ++mt) d[mt] = f32x4{0.f, 0.f, 0.f, 0.f};
                #pragma unroll
                for (int kk = 0; kk < 8; ++kk) {
                    s16x8 b = *((const s16x8*)pWdec + (wave * 8 + kk) * 64 + lane);
                    #pragma unroll
                    for (int mt = 0; mt < 4; ++mt) {
                        s16x8 a = *(const s16x8*)(h2w + (kk * 4 + mt) * 520 + lane * 8);
                        d[mt] = MFMA(a, b, d[mt]);
                    }
                }
                const int col = wave * 16 + ln15;
                const bool valid = (col < 34);
                const float bd = Lbd[col];
                #pragma unroll
                for (int mt = 0; mt < 4; ++mt) {
                    #pragma unroll
                    for (int r = 0; r < 4; ++r) {
                        const int rloc = mt * 16 + quad * 4 + r;
                        float v = d[mt][r] + bd;
                        if (tout == 0) {
                            float xr = valid ? __builtin_nontemporal_load(x + (m0 + rloc) * 340 + 306 + col) : 0.f;
                            dOut[rloc * 48 + col] = v + xr;
                        } else {
                            dOut[rloc * 48 + col] += v;
                        }
                    }
                }
            }
            __syncthreads();
            // contiguous per-row non-temporal stores
            for (int i = tid; i < 1088; i += 512) {
                int r = i / 17, p = i - r * 17;
                f32x2 v = *(const f32x2*)(dOut + r * 48 + p * 2);
                __builtin_nontemporal_store(v, (f32x2*)(out + (m0 + r) * 340 + tout * 34) + p);
            }
            // safe: staging only at t<10, decoder rewrite of dOut only after 2 cell barriers
        }
    }
}

// ---------------- launch ----------------

extern "C" void kernel_launch(void* const* d_in, const int* in_sizes, int n_in,
                              void* d_out, int out_size, void* d_ws, size_t ws_size,
                              hipStream_t stream) {
    const float* x     = (const float*)d_in[0];
    const float* W_enc = (const float*)d_in[1];
    const float* b_enc = (const float*)d_in[2];
    const float* Wih1  = (const float*)d_in[3];
    const float* Whh1  = (const float*)d_in[4];
    const float* bih1  = (const float*)d_in[5];
    const float* bhh1  = (const float*)d_in[6];
    const float* Wih2  = (const float*)d_in[7];
    const float* Whh2  = (const float*)d_in[8];
    const float* bih2  = (const float*)d_in[9];
    const float* bhh2  = (const float*)d_in[10];
    const float* W_dec = (const float*)d_in[11];
    const float* b_dec = (const float*)d_in[12];
    float* out = (float*)d_out;

    unsigned char* w = (unsigned char*)d_ws;
    float* WC   = (float*)(w + 0);         // 139264
    float* benc = (float*)(w + 139264);    // 4096
    float* bs1a = (float*)(w + 143360);
    float* bs1b = (float*)(w + 147456);
    float* bs2  = (float*)(w + 151552);
    float* bdec = (float*)(w + 155648);    // 256
    unsigned short* pWC   = (unsigned short*)(w + 155904);   // 131072
    unsigned short* pWih1 = (unsigned short*)(w + 286976);   // 524288 each
    unsigned short* pWhh1 = (unsigned short*)(w + 811264);
    unsigned short* pWih2 = (unsigned short*)(w + 1335552);
    unsigned short* pWhh2 = (unsigned short*)(w + 1859840);
    unsigned short* pWdec = (unsigned short*)(w + 2384128);  // 24576

    wc_kernel<<<140, 256, 0, stream>>>(Wih1, W_enc, b_enc, WC, benc);
    pack_kernel<<<32, 256, 0, stream>>>(WC, pWC, 16, 2, 4, 256, 1024, 34);
    pack_kernel<<<128, 256, 0, stream>>>(Wih1, pWih1, 16, 8, 4, 256, 1024, 256);
    pack_kernel<<<128, 256, 0, stream>>>(Whh1, pWhh1, 16, 8, 4, 256, 1024, 256);
    pack_kernel<<<128, 256, 0, stream>>>(Wih2, pWih2, 16, 8, 4, 256, 1024, 256);
    pack_kernel<<<128, 256, 0, stream>>>(Whh2, pWhh2, 16, 8, 4, 256, 1024, 256);
    pack_kernel<<<6, 256, 0, stream>>>(W_dec, pWdec, 3, 8, 1, 0, 34, 256);
    bias_kernel<<<4, 256, 0, stream>>>(bih1, bhh1, benc, bih2, bhh2, b_dec, bs1a, bs1b, bs2, bdec);

    hipFuncSetAttribute((const void*)lstm_fused, hipFuncAttributeMaxDynamicSharedMemorySize, 157952);
    lstm_fused<<<256, 512, 157952, stream>>>(x, pWC, pWih1, pWhh1, pWih2, pWhh2, pWdec,
                                             bs1a, bs1b, bs2, bdec, out);
}